// Round 12
// baseline (380.894 us; speedup 1.0000x reference)
//
#include <hip/hip_runtime.h>
#include <math.h>

// Problem constants (setup_inputs): B=8, C=64, N=4096, O=64, K=20
#define Bn 8
#define Cc 64
#define Nn 4096
#define Oo 64
#define Kk 20
#define Kh 10                // half-list size (rank-split pair handlers)
#define QCAP 32              // == max candidates/row/sub-tile -> no overflow
#define NTOT (Bn*Nn*Kk)      // 655360 elements per BN channel

typedef __attribute__((ext_vector_type(8))) short short8;
typedef __attribute__((ext_vector_type(4))) float f32x4;

__device__ __forceinline__ unsigned bf16_rn(float v) {
  unsigned u = __float_as_uint(v);
  return (u + 0x7FFFu + ((u >> 16) & 1)) >> 16;     // RN-even
}

// lane-pair swap (lane 2k <-> 2k+1) via DPP quad_perm [1,0,3,2]:
// 1-cycle VALU, no lgkm round-trip (vs ds_bpermute from __shfl_xor)
__device__ __forceinline__ float pair_swap_f(float v) {
  return __int_as_float(__builtin_amdgcn_mov_dpp(__float_as_int(v), 0xB1, 0xF, 0xF, true));
}
__device__ __forceinline__ int pair_swap_i(int v) {
  return __builtin_amdgcn_mov_dpp(v, 0xB1, 0xF, 0xF, true);
}

// async global->LDS, 16B per lane: LDS dest = wave-uniform base + lane*16,
// global src is per-lane. Size must be a literal (16).
__device__ __forceinline__ void gload_lds16(const void* g, void* l) {
  __builtin_amdgcn_global_load_lds((const __attribute__((address_space(1))) void*)g,
                                   (__attribute__((address_space(3))) void*)l,
                                   16, 0, 0);
}

// ---------------------------------------------------------------- k_pre
// FUSED k_split + k_y1z (layout A only): both kernels staged the SAME x
// tile into LDS; fusing saves one full 8MB x read, one LDS stage+sync and
// one kernel launch. Requires y1/z NOT overlaying xs3 (needs ~32.4MB ws).
__global__ __launch_bounds__(256) void k_pre(const float* __restrict__ x,
                                             const float* __restrict__ Wm,
                                             unsigned short* __restrict__ xs3,
                                             float* __restrict__ sqv,
                                             float* __restrict__ y1,
                                             float* __restrict__ z) {
  __shared__ float xs[64][68];                  // [c][n], float4-friendly pad
  __shared__ float Wl[64][129];
  int tid = threadIdx.x;
  int b = blockIdx.x & 7;
  int n0 = (blockIdx.x >> 3) << 6;
  for (int i = tid; i < 64 * 128; i += 256) Wl[i >> 7][i & 127] = Wm[i];
  for (int i = 0; i < 4; i++) {
    int c = i * 16 + (tid >> 4);
    int n = (tid & 15) * 4;
    float4 v = *(const float4*)&x[((size_t)b * Cc + c) * Nn + n0 + n];
    *(float4*)&xs[c][n] = v;
  }
  __syncthreads();
  // ---- split part: 3-term bf16 split, interleaved layout + sq
  for (int i = 0; i < 4; i++) {
    int n = i * 16 + (tid >> 4);
    int c = (tid & 15) * 4;
    ushort4 h4, m4, l4;
    unsigned short* hp = (unsigned short*)&h4;
    unsigned short* mp = (unsigned short*)&m4;
    unsigned short* lp = (unsigned short*)&l4;
#pragma unroll
    for (int j = 0; j < 4; j++) {
      float v = xs[c + j][n];
      unsigned hb = bf16_rn(v);
      float hf = __uint_as_float(hb << 16);
      float r1 = v - hf;                                     // exact
      unsigned mb = bf16_rn(r1);
      float mf = __uint_as_float(mb << 16);
      float r2 = r1 - mf;                                    // exact
      unsigned lb = bf16_rn(r2);
      hp[j] = (unsigned short)hb;
      mp[j] = (unsigned short)mb;
      lp[j] = (unsigned short)lb;
    }
    size_t o = ((size_t)(b << 12) + n0 + n) * 192 + c;
    *(ushort4*)&xs3[o] = h4;
    *(ushort4*)&xs3[o + 64] = m4;
    *(ushort4*)&xs3[o + 128] = l4;
  }
  if (tid < 64) {
    float s = 0.f;
#pragma unroll
    for (int c = 0; c < 64; c++) { float v = xs[c][tid]; s = fmaf(v, v, s); }
    sqv[b * Nn + n0 + tid] = s;
  }
  // ---- y1z part
  int o = tid & 63, ng = tid >> 6;              // ng == wave id -> nb uniform
  for (int p = 0; p < 4; p++) {
    int nb = p * 16 + ng * 4;
    float a1[4] = {0.f, 0.f, 0.f, 0.f};
    float a2[4] = {0.f, 0.f, 0.f, 0.f};
#pragma unroll 8
    for (int c = 0; c < 64; c++) {
      float4 xv = *(const float4*)&xs[c][nb];   // wave-broadcast
      float w1v = Wl[o][c], w2v = Wl[o][64 + c];
      float xa[4] = {xv.x, xv.y, xv.z, xv.w};
#pragma unroll
      for (int j = 0; j < 4; j++) {
        a1[j] = fmaf(xa[j], w1v, a1[j]);
        a2[j] = fmaf(xa[j], w2v, a2[j]);
      }
    }
#pragma unroll
    for (int j = 0; j < 4; j++) {
      size_t off = ((size_t)b * Nn + n0 + nb + j) * 64 + o;
      y1[off] = a1[j];
      z[off] = a2[j] - a1[j];
    }
  }
}

// ---------------------------------------------------------------- k_split
// (fallback layout B only) x fp32 [b][c][n] -> xs3 + sq
__global__ __launch_bounds__(256) void k_split(const float* __restrict__ x,
                                               unsigned short* __restrict__ xs3,
                                               float* __restrict__ sqv) {
  __shared__ float xs[64][68];                  // [c][n], float4-friendly pad
  int tid = threadIdx.x;
  int b = blockIdx.x & 7;
  int n0 = (blockIdx.x >> 3) << 6;
  for (int i = 0; i < 4; i++) {
    int c = i * 16 + (tid >> 4);
    int n = (tid & 15) * 4;
    float4 v = *(const float4*)&x[((size_t)b * Cc + c) * Nn + n0 + n];
    *(float4*)&xs[c][n] = v;
  }
  __syncthreads();
  for (int i = 0; i < 4; i++) {
    int n = i * 16 + (tid >> 4);
    int c = (tid & 15) * 4;
    ushort4 h4, m4, l4;
    unsigned short* hp = (unsigned short*)&h4;
    unsigned short* mp = (unsigned short*)&m4;
    unsigned short* lp = (unsigned short*)&l4;
#pragma unroll
    for (int j = 0; j < 4; j++) {
      float v = xs[c + j][n];
      unsigned hb = bf16_rn(v);
      float hf = __uint_as_float(hb << 16);
      float r1 = v - hf;                                     // exact
      unsigned mb = bf16_rn(r1);
      float mf = __uint_as_float(mb << 16);
      float r2 = r1 - mf;                                    // exact
      unsigned lb = bf16_rn(r2);
      hp[j] = (unsigned short)hb;
      mp[j] = (unsigned short)mb;
      lp[j] = (unsigned short)lb;
    }
    size_t o = ((size_t)(b << 12) + n0 + n) * 192 + c;
    *(ushort4*)&xs3[o] = h4;
    *(ushort4*)&xs3[o + 64] = m4;
    *(ushort4*)&xs3[o + 128] = l4;
  }
  if (tid < 64) {
    float s = 0.f;
#pragma unroll
    for (int c = 0; c < 64; c++) { float v = xs[c][tid]; s = fmaf(v, v, s); }
    sqv[b * Nn + n0 + tid] = s;
  }
}

// ---------------------------------------------------------------- k_y1z
// (fallback layout B only)
__global__ __launch_bounds__(256) void k_y1z(const float* __restrict__ x,
                                             const float* __restrict__ Wm,
                                             float* __restrict__ y1,
                                             float* __restrict__ z) {
  __shared__ float xs[64][68];                  // [c][n]
  __shared__ float Wl[64][129];
  int tid = threadIdx.x;
  int b = blockIdx.x & 7;
  int n0 = (blockIdx.x >> 3) << 6;
  for (int i = tid; i < 64 * 128; i += 256) Wl[i >> 7][i & 127] = Wm[i];
  for (int i = 0; i < 4; i++) {
    int c = i * 16 + (tid >> 4);
    int n = (tid & 15) * 4;
    float4 v = *(const float4*)&x[((size_t)b * Cc + c) * Nn + n0 + n];
    *(float4*)&xs[c][n] = v;
  }
  __syncthreads();
  int o = tid & 63, ng = tid >> 6;              // ng == wave id -> nb uniform
  for (int p = 0; p < 4; p++) {
    int nb = p * 16 + ng * 4;
    float a1[4] = {0.f, 0.f, 0.f, 0.f};
    float a2[4] = {0.f, 0.f, 0.f, 0.f};
#pragma unroll 8
    for (int c = 0; c < 64; c++) {
      float4 xv = *(const float4*)&xs[c][nb];   // wave-broadcast
      float w1v = Wl[o][c], w2v = Wl[o][64 + c];
      float xa[4] = {xv.x, xv.y, xv.z, xv.w};
#pragma unroll
      for (int j = 0; j < 4; j++) {
        a1[j] = fmaf(xa[j], w1v, a1[j]);
        a2[j] = fmaf(xa[j], w2v, a2[j]);
      }
    }
#pragma unroll
    for (int j = 0; j < 4; j++) {
      size_t off = ((size_t)b * Nn + n0 + nb + j) * 64 + o;
      y1[off] = a1[j];
      z[off] = a2[j] - a1[j];
    }
  }
}

// ---------------------------------------------------------------- k_knn (v21)
// r8's best structure (237.4us), unchanged since r10: sub-tile double-buffer
// global_load_lds pipeline, XOR-linear staging, atomicAdd push, pair
// handlers, one-way threshold sharing (g1 takes min(thr1,thr0), r3-proven).
// All structural levers A/B-measured: ballot push +48us, quad drain +100us,
// bidir thresholds +26us (reverted); pipeline/conflict-fix/async neutral.
__global__ __launch_bounds__(512, 4) void k_knn(const unsigned short* __restrict__ xs3,
                                                const float* __restrict__ sqv,
                                                int* __restrict__ idxout) {
  __shared__ alignas(16) short Bs[2][2][6144];   // [grp][buf][32x192, XOR-swizzled]
  __shared__ alignas(16) float thrS[2][64];
  __shared__ alignas(16) float sqs[2][2][32];    // [grp][buf][col]
  __shared__ alignas(16) float qk[2][64][36];    // 144B rows: aligned + 2-way
  __shared__ alignas(16) unsigned short qm[2][64][40]; // 80B rows
  __shared__ int qcnt[2][64];

  const int tid = threadIdx.x;
  const int lane = tid & 63;
  const int w = tid >> 6;                        // 0..7
  const int grp = w >> 2;                        // m-range group
  const int wg = w & 3;                          // wave within group
  const int tig = tid & 255;                     // thread within group
  const int b = blockIdx.x & 7;                  // XCD swizzle: batch per XCD
  const int n0 = (blockIdx.x >> 3) << 6;         // 64 row-blocks x 64 rows
  const int lm = lane & 15;                      // candidate col / A row slot
  const int q = lane >> 4;                       // quad: C row = q*4+r
  const bool handler = (lane < 32);
  const int hrow = wg * 16 + (lane >> 1);        // row for this handler pair
  const bool isL = (lane & 1) == 0;              // L = ranks 0-9, H = 10-19
  const int rowq = wg * 16 + q * 4;              // my 4 push rows base

  // handler half-list: sorted ascending 10-list in registers
  float hk[Kh];
  int hix[Kh];
#pragma unroll
  for (int kk = 0; kk < Kh; kk++) { hk[kk] = INFINITY; hix[kk] = 0; }

  if (handler && !isL) { thrS[grp][hrow] = INFINITY; qcnt[grp][hrow] = 0; }

  // A fragments: wave owns 16 DISTINCT rows n0 + wg*16 + lm
  const size_t arow = ((size_t)(b << 12) + n0 + wg * 16 + lm) * 192;
  short8 ah0 = *(const short8*)&xs3[arow + q * 8];
  short8 ah1 = *(const short8*)&xs3[arow + 32 + q * 8];
  short8 am0 = *(const short8*)&xs3[arow + 64 + q * 8];
  short8 am1 = *(const short8*)&xs3[arow + 96 + q * 8];
  short8 al0 = *(const short8*)&xs3[arow + 128 + q * 8];
  short8 al1 = *(const short8*)&xs3[arow + 160 + q * 8];

  // ---- staging geometry: sub-tile = 32 rows x 24 granules = 768 granules.
  // LDS granule p holds global granule p ^ ((p/24)&7) (involution; rows are
  // 24 granules so aligned-8 blocks are row-pure). Wave wg, chunk i covers
  // LDS granules [i*256 + wg*64, +64): lane l -> p = that + l.
  const unsigned short* gbase = xs3 + ((size_t)(b << 12) + grp * 2048) * 192;
  int gofs[3];                                   // per-lane global short offs
  int lofs[3];                                   // wave-uniform LDS short offs
#pragma unroll
  for (int i = 0; i < 3; i++) {
    int p = i * 256 + wg * 64 + lane;
    gofs[i] = (p ^ ((p / 24) & 7)) * 8;
    lofs[i] = (i * 256 + wg * 64) * 8;
  }
  // B-fragment read XOR terms: row = g*16+lm -> row&7 == lm&7
  const int qa = ((q ^ (lm & 7)) << 3);          // granule q   (cols 0-31)
  const int qb = (((q + 4) ^ (lm & 7)) << 3);    // granule q+4 (cols 32-63)

  // prologue: stage sub-tile 0 into buf 0
#pragma unroll
  for (int i = 0; i < 3; i++) gload_lds16(gbase + gofs[i], &Bs[grp][0][lofs[i]]);
  if (tig < 8) gload_lds16(sqv + b * Nn + grp * 2048 + lane * 4, &sqs[grp][0][0]);

  int cur = 0;
  for (int t = 0; t < 64; t++) {
    const int m0 = grp * 2048 + t * 32;
    __syncthreads();             // buf[cur] loads landed; buf[cur^1] released
    if (t < 63) {                // prefetch next sub-tile under compute+drain
      const unsigned short* gn = gbase + 6144;
#pragma unroll
      for (int i = 0; i < 3; i++) gload_lds16(gn + gofs[i], &Bs[grp][cur ^ 1][lofs[i]]);
      if (tig < 8) gload_lds16(sqv + b * Nn + m0 + 32 + lane * 4, &sqs[grp][cur ^ 1][0]);
      gbase = gn;
    }

    const short* Bg = &Bs[grp][cur][0];
    f32x4 acc[2];
#pragma unroll
    for (int g = 0; g < 2; g++) {
      const short* brow = Bg + (g * 16 + lm) * 192;
      short8 bh0 = *(const short8*)(brow + qa);
      short8 bh1 = *(const short8*)(brow + qb);
      short8 bm0 = *(const short8*)(brow + 64 + qa);
      short8 bm1 = *(const short8*)(brow + 64 + qb);
      short8 bl0 = *(const short8*)(brow + 128 + qa);
      short8 bl1 = *(const short8*)(brow + 128 + qb);
      f32x4 a = (f32x4){0.f, 0.f, 0.f, 0.f};
      a = __builtin_amdgcn_mfma_f32_16x16x32_bf16(am0, bm0, a, 0, 0, 0);  // mm
      a = __builtin_amdgcn_mfma_f32_16x16x32_bf16(am1, bm1, a, 0, 0, 0);
      a = __builtin_amdgcn_mfma_f32_16x16x32_bf16(ah0, bl0, a, 0, 0, 0);  // hl
      a = __builtin_amdgcn_mfma_f32_16x16x32_bf16(ah1, bl1, a, 0, 0, 0);
      a = __builtin_amdgcn_mfma_f32_16x16x32_bf16(al0, bh0, a, 0, 0, 0);  // lh
      a = __builtin_amdgcn_mfma_f32_16x16x32_bf16(al1, bh1, a, 0, 0, 0);
      a = __builtin_amdgcn_mfma_f32_16x16x32_bf16(ah0, bm0, a, 0, 0, 0);  // hm
      a = __builtin_amdgcn_mfma_f32_16x16x32_bf16(ah1, bm1, a, 0, 0, 0);
      a = __builtin_amdgcn_mfma_f32_16x16x32_bf16(am0, bh0, a, 0, 0, 0);  // mh
      a = __builtin_amdgcn_mfma_f32_16x16x32_bf16(am1, bh1, a, 0, 0, 0);
      a = __builtin_amdgcn_mfma_f32_16x16x32_bf16(ah0, bh0, a, 0, 0, 0);  // hh
      a = __builtin_amdgcn_mfma_f32_16x16x32_bf16(ah1, bh1, a, 0, 0, 0);
      acc[g] = a;
    }

    // keys = sq[m] - 2*dot; 8 keys/lane (2 g x 4 r)
    unsigned pend = 0;
    {
      float4 t4 = *(const float4*)&thrS[grp][rowq];
      float tl[4] = {t4.x, t4.y, t4.z, t4.w};
      if (grp) {                                  // safe direction only (r3)
        float4 s4 = *(const float4*)&thrS[0][rowq];
        tl[0] = fminf(tl[0], s4.x); tl[1] = fminf(tl[1], s4.y);
        tl[2] = fminf(tl[2], s4.z); tl[3] = fminf(tl[3], s4.w);
      }
#pragma unroll
      for (int g = 0; g < 2; g++) {
        float sv = sqs[grp][cur][g * 16 + lm];
#pragma unroll
        for (int r = 0; r < 4; r++) {
          float key = fmaf(-2.f, acc[g][r], sv);
          acc[g][r] = key;
          if (key < tl[r]) pend |= 1u << (g * 4 + r);
        }
      }
    }

    // push: queue can't overflow (<=32 candidates/row, QCAP 32) -> no retry
    if (pend) {
#pragma unroll
      for (int g = 0; g < 2; g++) {
#pragma unroll
        for (int r = 0; r < 4; r++) {
          unsigned bit = 1u << (g * 4 + r);
          if (pend & bit) {
            int row = rowq + r;
            int p = atomicAdd(&qcnt[grp][row], 1);
            qk[grp][row][p] = acc[g][r];
            qm[grp][row][p] = (unsigned short)(m0 + g * 16 + lm);
          }
        }
      }
    }

    // single drain round (wave-private rows; DS in-order per wave)
    if (handler) {                               // 32 lanes: 16 rows x (L,H)
      int cn = qcnt[grp][hrow];                  // same for both pair lanes
      for (int p0 = 0; p0 < cn; p0 += 2) {
        float2 kv2 = *(const float2*)&qk[grp][hrow][p0];     // pair-broadcast
        ushort2 mv2 = *(const ushort2*)&qm[grp][hrow][p0];
        float kva[2] = {kv2.x, kv2.y};
        unsigned short mva[2] = {mv2.x, mv2.y};
#pragma unroll
        for (int j = 0; j < 2; j++) {
          bool valid = (p0 + j < cn);
          float kv = kva[j];
          int ki = (int)mva[j];
          // L decides what flows to H: its evicted max, or kv itself
          bool lins = kv < hk[Kh - 1];
          float pv_ = lins ? hk[Kh - 1] : kv;
          int pi_ = lins ? hix[Kh - 1] : ki;
          float rv = pair_swap_f(pv_);
          int ri = pair_swap_i(pi_);
          float mval = isL ? kv : rv;
          int midx = isL ? ki : ri;
          if (valid && mval < hk[Kh - 1]) {      // both roles: same 10-insert
            bool cm[Kh];
#pragma unroll
            for (int kk = 0; kk < Kh; kk++) cm[kk] = mval < hk[kk];
#pragma unroll
            for (int kk = Kh - 1; kk >= 1; kk--) {
              hk[kk]  = cm[kk] ? (cm[kk - 1] ? hk[kk - 1]  : mval) : hk[kk];
              hix[kk] = cm[kk] ? (cm[kk - 1] ? hix[kk - 1] : midx) : hix[kk];
            }
            if (cm[0]) { hk[0] = mval; hix[0] = midx; }
          }
        }
      }
      if (cn && !isL) { qcnt[grp][hrow] = 0; thrS[grp][hrow] = hk[Kh - 1]; }
    }
    cur ^= 1;
  }

  // -------- merge: group 1 publishes its rank-sorted 20-list per row
  if (grp == 1 && handler) {
    int base = isL ? 0 : Kh;
#pragma unroll
    for (int kk = 0; kk < Kh; kk++) {
      qk[1][hrow][base + kk] = hk[kk];
      qm[1][hrow][base + kk] = (unsigned short)hix[kk];
    }
  }
  __syncthreads();
  if (grp == 0 && handler) {
    // feed group 1's 20 candidates (ascending key order) through the same
    // pair-insert machinery; group-1 m-indices are all >= 2048 > any
    // group-0 index, so strict '<' keeps sequential-scan tie semantics
    for (int p0 = 0; p0 < Kk; p0 += 4) {
      float4 kv4 = *(const float4*)&qk[1][hrow][p0];
      ushort4 mv4 = *(const ushort4*)&qm[1][hrow][p0];
      float kva[4] = {kv4.x, kv4.y, kv4.z, kv4.w};
      unsigned short mva[4] = {mv4.x, mv4.y, mv4.z, mv4.w};
#pragma unroll
      for (int j = 0; j < 4; j++) {
        float kv = kva[j];
        int ki = (int)mva[j];
        bool lins = kv < hk[Kh - 1];
        float pv_ = lins ? hk[Kh - 1] : kv;
        int pi_ = lins ? hix[Kh - 1] : ki;
        float rv = pair_swap_f(pv_);
        int ri = pair_swap_i(pi_);
        float mval = isL ? kv : rv;
        int midx = isL ? ki : ri;
        if (mval < hk[Kh - 1]) {
          bool cm[Kh];
#pragma unroll
          for (int kk = 0; kk < Kh; kk++) cm[kk] = mval < hk[kk];
#pragma unroll
          for (int kk = Kh - 1; kk >= 1; kk--) {
            hk[kk]  = cm[kk] ? (cm[kk - 1] ? hk[kk - 1]  : mval) : hk[kk];
            hix[kk] = cm[kk] ? (cm[kk - 1] ? hix[kk - 1] : midx) : hix[kk];
          }
          if (cm[0]) { hk[0] = mval; hix[0] = midx; }
        }
      }
    }
    // final write: L lane writes ranks 0-9, H lane ranks 10-19
    size_t obase = ((size_t)b * Nn + n0 + hrow) * Kk + (isL ? 0 : Kh);
#pragma unroll
    for (int kk = 0; kk < Kh; kk++) idxout[obase + kk] = hix[kk];
  }
}

// ---------------------------------------------------------------- k_stats32
// The single gather pass, OCCUPANCY-FIXED: the old 64-row tile's 35KB of
// LDS transpose buffers capped occupancy at 2 blocks/CU (8 waves) -- the
// ~200cy L2 gather latency (320 loads/thread) was barely hidden and the
// kernel ran ~7x over its memory floor. 32-row tiles: LDS 19KB -> 8
// blocks/CU (32 waves, full), grid 1024, same total work.
// Tmx/Tmn [64][33]: stride 33 == 1 mod 32 -> conflict-free both phases.
__global__ __launch_bounds__(256) void k_stats32(const float* __restrict__ y1,
                                                 const float* __restrict__ z,
                                                 const int* __restrict__ idxp,
                                                 float* __restrict__ parts,
                                                 float* __restrict__ hmax,
                                                 float* __restrict__ hmin) {
  __shared__ float rs[4][64];
  __shared__ float rq[4][64];
  __shared__ float Tmx[64][33];
  __shared__ float Tmn[64][33];
  int tid = threadIdx.x;
  int o = tid & 63, g = tid >> 6;
  int b = blockIdx.x & 7;                       // XCD swizzle
  int n0 = (blockIdx.x >> 3) << 5;              // 128 n-blocks x 32 rows
  const float* y1b = y1 + (size_t)b * Nn * 64;
  float s = 0.f, ss = 0.f;
  for (int t = 0; t < 8; t++) {
    int nl = g + t * 4;
    size_t base = (size_t)b * Nn + n0 + nl;
    float zv = z[base * 64 + o];
    const int* ip = idxp + base * Kk;
    float mx = -INFINITY, mn = INFINITY;
#pragma unroll
    for (int k = 0; k < Kk; k++) {
      int j = ip[k];
      float hv = y1b[(size_t)j * 64 + o] + zv;
      s += hv;
      ss = fmaf(hv, hv, ss);
      mx = fmaxf(mx, hv);
      mn = fminf(mn, hv);
    }
    Tmx[o][nl] = mx;
    Tmn[o][nl] = mn;
  }
  rs[g][o] = s;
  rq[g][o] = ss;
  __syncthreads();
  if (tid < 64) {
    parts[(size_t)blockIdx.x * 128 + tid] = rs[0][tid] + rs[1][tid] + rs[2][tid] + rs[3][tid];
    parts[(size_t)blockIdx.x * 128 + 64 + tid] = rq[0][tid] + rq[1][tid] + rq[2][tid] + rq[3][tid];
  }
  for (int t = 0; t < 8; t++) {
    int idx = t * 256 + tid;
    int oo = idx >> 5, col = idx & 31;
    size_t ob = ((size_t)b * Oo + oo) * Nn + n0 + col;
    hmax[ob] = Tmx[oo][col];
    hmin[ob] = Tmn[oo][col];
  }
}

// ---------------------------------------------------------------- k_stats
// (fallback layout B only: old 64-row version)
__global__ __launch_bounds__(256) void k_stats(const float* __restrict__ y1,
                                               const float* __restrict__ z,
                                               const int* __restrict__ idxp,
                                               float* __restrict__ parts,
                                               float* __restrict__ hmax,
                                               float* __restrict__ hmin) {
  __shared__ float rs[4][64];
  __shared__ float rq[4][64];
  __shared__ float Tmx[64][65];
  __shared__ float Tmn[64][65];
  int tid = threadIdx.x;
  int o = tid & 63, g = tid >> 6;
  int b = blockIdx.x & 7;                       // XCD swizzle
  int n0 = (blockIdx.x >> 3) << 6;
  const float* y1b = y1 + (size_t)b * Nn * 64;
  float s = 0.f, ss = 0.f;
  for (int t = 0; t < 16; t++) {
    int nl = g + t * 4;
    size_t base = (size_t)b * Nn + n0 + nl;
    float zv = z[base * 64 + o];
    const int* ip = idxp + base * Kk;
    float mx = -INFINITY, mn = INFINITY;
#pragma unroll
    for (int k = 0; k < Kk; k++) {
      int j = ip[k];
      float hv = y1b[(size_t)j * 64 + o] + zv;
      s += hv;
      ss = fmaf(hv, hv, ss);
      mx = fmaxf(mx, hv);
      mn = fminf(mn, hv);
    }
    Tmx[o][nl] = mx;
    Tmn[o][nl] = mn;
  }
  rs[g][o] = s;
  rq[g][o] = ss;
  __syncthreads();
  if (tid < 64) {
    parts[(size_t)blockIdx.x * 128 + tid] = rs[0][tid] + rs[1][tid] + rs[2][tid] + rs[3][tid];
    parts[(size_t)blockIdx.x * 128 + 64 + tid] = rq[0][tid] + rq[1][tid] + rq[2][tid] + rq[3][tid];
  }
  int lane = tid & 63;
  for (int t = 0; t < 16; t++) {
    int oo = g * 16 + t;
    size_t ob = ((size_t)b * Oo + oo) * Nn + n0 + lane;
    hmax[ob] = Tmx[oo][lane];
    hmin[ob] = Tmn[oo][lane];
  }
}

// ---------------------------------------------------------------- k_reduce
// deterministic fixed-order pass; nrows parameterizes the partial count
// (1024 for 32-row k_stats32, 512 for the fallback).
__global__ __launch_bounds__(128) void k_reduce(const float* __restrict__ parts,
                                                float* __restrict__ stats,
                                                int nrows) {
  int tid = threadIdx.x;                         // [0,128)
  float s = 0.f;
  for (int i = 0; i < nrows; i += 4) {
    s += parts[(size_t)i * 128 + tid] + parts[(size_t)(i + 1) * 128 + tid] +
         parts[(size_t)(i + 2) * 128 + tid] + parts[(size_t)(i + 3) * 128 + tid];
  }
  stats[tid] = s;
}

// ---------------------------------------------------------------- k_out (v2)
// Pure elementwise: max_k leaky(sc*hv+bi) = leaky(sc*(sc>=0?max:min)+bi)
// (leaky-relu monotone increasing; affine orientation from sign of sc).
// hmax lives in the out buffer -> in-place read/modify/write.
__global__ __launch_bounds__(256) void k_out(const float* __restrict__ hmax,
                                             const float* __restrict__ hmin,
                                             const float* __restrict__ stats,
                                             const float* __restrict__ gamma,
                                             const float* __restrict__ beta,
                                             float* __restrict__ out) {
  int idx4 = blockIdx.x * 256 + threadIdx.x;     // 2048 blocks x 256 = 524288
  int o = (idx4 >> 10) & 63;                     // Nn/4 = 1024 float4 per (b,o)
  const float inv = 1.0f / (float)NTOT;
  float mean = stats[o] * inv;
  float var = fmaf(-mean, mean, stats[64 + o] * inv);
  float sc = gamma[o] * rsqrtf(var + 1e-5f);
  float bi = fmaf(-mean, sc, beta[o]);
  float4 mx = ((const float4*)hmax)[idx4];
  float4 mn = ((const float4*)hmin)[idx4];
  float mxa[4] = {mx.x, mx.y, mx.z, mx.w};
  float mna[4] = {mn.x, mn.y, mn.z, mn.w};
  float4 r;
  float* rp = (float*)&r;
#pragma unroll
  for (int j = 0; j < 4; j++) {
    float v = (sc >= 0.f) ? mxa[j] : mna[j];
    float hn = fmaf(v, sc, bi);
    rp[j] = (hn >= 0.f) ? hn : 0.2f * hn;
  }
  ((float4*)out)[idx4] = r;
}

// ---------------------------------------------------------------- launch
extern "C" void kernel_launch(void* const* d_in, const int* in_sizes, int n_in,
                              void* d_out, int out_size, void* d_ws, size_t ws_size,
                              hipStream_t stream) {
  const float* x = (const float*)d_in[0];
  const float* W = (const float*)d_in[1];
  const float* gamma = (const float*)d_in[2];
  const float* beta = (const float*)d_in[3];
  // d_in[4] is k (=20), baked in as Kk.
  char* ws = (char*)d_ws;
  float* out = (float*)d_out;

  if (ws_size >= 32375296) {
    // ---- layout A (no xs3/y1 overlay -> k_split+k_y1z fused into k_pre):
    //   xs3  : [0,       12582912)   bf16 interleaved (dead after k_knn;
    //                                 hmin overlays [0, 8388608) and parts
    //                                 overlays [8388608, 8912896) in k_stats)
    //   y1   : [12582912,20971520)
    //   z    : [20971520,29360128)
    //   sq   : [29360128,29491200)
    //   stats: [29491200,29491712)
    //   idx20: [29491712,32113152)
    unsigned short* xs3 = (unsigned short*)ws;
    float* y1 = (float*)(ws + 12582912);
    float* z = (float*)(ws + 20971520);
    float* sq = (float*)(ws + 29360128);
    float* stats = (float*)(ws + 29491200);
    int* idx = (int*)(ws + 29491712);
    float* hmin = (float*)ws;                   // overlay dead xs3
    float* parts = (float*)(ws + 8388608);      // overlay dead xs3 (512KB)

    k_pre<<<Bn * (Nn / 64), 256, 0, stream>>>(x, W, xs3, sq, y1, z);
    k_knn<<<Bn * (Nn / 64), 512, 0, stream>>>(xs3, sq, idx);
    k_stats32<<<Bn * (Nn / 32), 256, 0, stream>>>(y1, z, idx, parts, out, hmin);
    k_reduce<<<1, 128, 0, stream>>>(parts, stats, 1024);
    k_out<<<Bn * Oo * Nn / 1024, 256, 0, stream>>>(out, hmin, stats, gamma, beta, out);
  } else {
    // ---- layout B (r10 fallback; y1/z overlay xs3 -> k_y1z after k_knn):
    //   xs3 [0,12582912) / y1 [0,8388608) / z [8388608,16777216)
    //   sq [16777216,16908288) / stats [16908288,16908800)
    //   idx [16908800,19530240) / parts [19530240,19792384)
    //   hmin [19792384,28180992)
    unsigned short* xs3 = (unsigned short*)ws;
    float* y1 = (float*)ws;
    float* z = (float*)(ws + 8388608);
    float* sq = (float*)(ws + 16777216);
    float* stats = (float*)(ws + 16908288);
    int* idx = (int*)(ws + 16908800);
    float* parts = (float*)(ws + 19530240);
    float* hmin = (float*)(ws + 19792384);

    k_split<<<Bn * (Nn / 64), 256, 0, stream>>>(x, xs3, sq);
    k_knn<<<Bn * (Nn / 64), 512, 0, stream>>>(xs3, sq, idx);
    k_y1z<<<Bn * (Nn / 64), 256, 0, stream>>>(x, W, y1, z);
    k_stats<<<Bn * (Nn / 64), 256, 0, stream>>>(y1, z, idx, parts, out, hmin);
    k_reduce<<<1, 128, 0, stream>>>(parts, stats, 512);
    k_out<<<Bn * Oo * Nn / 1024, 256, 0, stream>>>(out, hmin, stats, gamma, beta, out);
  }
}

// Round 13
// 331.155 us; speedup vs baseline: 1.1502x; 1.1502x over previous
//
#include <hip/hip_runtime.h>
#include <math.h>

// Problem constants (setup_inputs): B=8, C=64, N=4096, O=64, K=20
#define Bn 8
#define Cc 64
#define Nn 4096
#define Oo 64
#define Kk 20
#define Kh 10                // half-list size (rank-split pair handlers)
#define QCAP 32              // == max candidates/row/sub-tile -> no overflow
#define NTOT (Bn*Nn*Kk)      // 655360 elements per BN channel

typedef __attribute__((ext_vector_type(8))) short short8;
typedef __attribute__((ext_vector_type(4))) float f32x4;

__device__ __forceinline__ unsigned bf16_rn(float v) {
  unsigned u = __float_as_uint(v);
  return (u + 0x7FFFu + ((u >> 16) & 1)) >> 16;     // RN-even
}

// lane-pair swap (lane 2k <-> 2k+1) via DPP quad_perm [1,0,3,2]:
// 1-cycle VALU, no lgkm round-trip (vs ds_bpermute from __shfl_xor)
__device__ __forceinline__ float pair_swap_f(float v) {
  return __int_as_float(__builtin_amdgcn_mov_dpp(__float_as_int(v), 0xB1, 0xF, 0xF, true));
}
__device__ __forceinline__ int pair_swap_i(int v) {
  return __builtin_amdgcn_mov_dpp(v, 0xB1, 0xF, 0xF, true);
}

// async global->LDS, 16B per lane: LDS dest = wave-uniform base + lane*16,
// global src is per-lane. Size must be a literal (16).
__device__ __forceinline__ void gload_lds16(const void* g, void* l) {
  __builtin_amdgcn_global_load_lds((const __attribute__((address_space(1))) void*)g,
                                   (__attribute__((address_space(3))) void*)l,
                                   16, 0, 0);
}

// ---------------------------------------------------------------- k_pre
// FUSED k_split + k_y1z (layout A only): both kernels staged the SAME x
// tile into LDS; fusing saves one full 8MB x read, one LDS stage+sync and
// one kernel launch. Requires y1/z NOT overlaying xs3 (needs ~32.4MB ws).
__global__ __launch_bounds__(256) void k_pre(const float* __restrict__ x,
                                             const float* __restrict__ Wm,
                                             unsigned short* __restrict__ xs3,
                                             float* __restrict__ sqv,
                                             float* __restrict__ y1,
                                             float* __restrict__ z) {
  __shared__ float xs[64][68];                  // [c][n], float4-friendly pad
  __shared__ float Wl[64][129];
  int tid = threadIdx.x;
  int b = blockIdx.x & 7;
  int n0 = (blockIdx.x >> 3) << 6;
  for (int i = tid; i < 64 * 128; i += 256) Wl[i >> 7][i & 127] = Wm[i];
  for (int i = 0; i < 4; i++) {
    int c = i * 16 + (tid >> 4);
    int n = (tid & 15) * 4;
    float4 v = *(const float4*)&x[((size_t)b * Cc + c) * Nn + n0 + n];
    *(float4*)&xs[c][n] = v;
  }
  __syncthreads();
  // ---- split part: 3-term bf16 split, interleaved layout + sq
  for (int i = 0; i < 4; i++) {
    int n = i * 16 + (tid >> 4);
    int c = (tid & 15) * 4;
    ushort4 h4, m4, l4;
    unsigned short* hp = (unsigned short*)&h4;
    unsigned short* mp = (unsigned short*)&m4;
    unsigned short* lp = (unsigned short*)&l4;
#pragma unroll
    for (int j = 0; j < 4; j++) {
      float v = xs[c + j][n];
      unsigned hb = bf16_rn(v);
      float hf = __uint_as_float(hb << 16);
      float r1 = v - hf;                                     // exact
      unsigned mb = bf16_rn(r1);
      float mf = __uint_as_float(mb << 16);
      float r2 = r1 - mf;                                    // exact
      unsigned lb = bf16_rn(r2);
      hp[j] = (unsigned short)hb;
      mp[j] = (unsigned short)mb;
      lp[j] = (unsigned short)lb;
    }
    size_t o = ((size_t)(b << 12) + n0 + n) * 192 + c;
    *(ushort4*)&xs3[o] = h4;
    *(ushort4*)&xs3[o + 64] = m4;
    *(ushort4*)&xs3[o + 128] = l4;
  }
  if (tid < 64) {
    float s = 0.f;
#pragma unroll
    for (int c = 0; c < 64; c++) { float v = xs[c][tid]; s = fmaf(v, v, s); }
    sqv[b * Nn + n0 + tid] = s;
  }
  // ---- y1z part
  int o = tid & 63, ng = tid >> 6;              // ng == wave id -> nb uniform
  for (int p = 0; p < 4; p++) {
    int nb = p * 16 + ng * 4;
    float a1[4] = {0.f, 0.f, 0.f, 0.f};
    float a2[4] = {0.f, 0.f, 0.f, 0.f};
#pragma unroll 8
    for (int c = 0; c < 64; c++) {
      float4 xv = *(const float4*)&xs[c][nb];   // wave-broadcast
      float w1v = Wl[o][c], w2v = Wl[o][64 + c];
      float xa[4] = {xv.x, xv.y, xv.z, xv.w};
#pragma unroll
      for (int j = 0; j < 4; j++) {
        a1[j] = fmaf(xa[j], w1v, a1[j]);
        a2[j] = fmaf(xa[j], w2v, a2[j]);
      }
    }
#pragma unroll
    for (int j = 0; j < 4; j++) {
      size_t off = ((size_t)b * Nn + n0 + nb + j) * 64 + o;
      y1[off] = a1[j];
      z[off] = a2[j] - a1[j];
    }
  }
}

// ---------------------------------------------------------------- k_split
// (fallback layout B only) x fp32 [b][c][n] -> xs3 + sq
__global__ __launch_bounds__(256) void k_split(const float* __restrict__ x,
                                               unsigned short* __restrict__ xs3,
                                               float* __restrict__ sqv) {
  __shared__ float xs[64][68];                  // [c][n], float4-friendly pad
  int tid = threadIdx.x;
  int b = blockIdx.x & 7;
  int n0 = (blockIdx.x >> 3) << 6;
  for (int i = 0; i < 4; i++) {
    int c = i * 16 + (tid >> 4);
    int n = (tid & 15) * 4;
    float4 v = *(const float4*)&x[((size_t)b * Cc + c) * Nn + n0 + n];
    *(float4*)&xs[c][n] = v;
  }
  __syncthreads();
  for (int i = 0; i < 4; i++) {
    int n = i * 16 + (tid >> 4);
    int c = (tid & 15) * 4;
    ushort4 h4, m4, l4;
    unsigned short* hp = (unsigned short*)&h4;
    unsigned short* mp = (unsigned short*)&m4;
    unsigned short* lp = (unsigned short*)&l4;
#pragma unroll
    for (int j = 0; j < 4; j++) {
      float v = xs[c + j][n];
      unsigned hb = bf16_rn(v);
      float hf = __uint_as_float(hb << 16);
      float r1 = v - hf;                                     // exact
      unsigned mb = bf16_rn(r1);
      float mf = __uint_as_float(mb << 16);
      float r2 = r1 - mf;                                    // exact
      unsigned lb = bf16_rn(r2);
      hp[j] = (unsigned short)hb;
      mp[j] = (unsigned short)mb;
      lp[j] = (unsigned short)lb;
    }
    size_t o = ((size_t)(b << 12) + n0 + n) * 192 + c;
    *(ushort4*)&xs3[o] = h4;
    *(ushort4*)&xs3[o + 64] = m4;
    *(ushort4*)&xs3[o + 128] = l4;
  }
  if (tid < 64) {
    float s = 0.f;
#pragma unroll
    for (int c = 0; c < 64; c++) { float v = xs[c][tid]; s = fmaf(v, v, s); }
    sqv[b * Nn + n0 + tid] = s;
  }
}

// ---------------------------------------------------------------- k_y1z
// (fallback layout B only)
__global__ __launch_bounds__(256) void k_y1z(const float* __restrict__ x,
                                             const float* __restrict__ Wm,
                                             float* __restrict__ y1,
                                             float* __restrict__ z) {
  __shared__ float xs[64][68];                  // [c][n]
  __shared__ float Wl[64][129];
  int tid = threadIdx.x;
  int b = blockIdx.x & 7;
  int n0 = (blockIdx.x >> 3) << 6;
  for (int i = tid; i < 64 * 128; i += 256) Wl[i >> 7][i & 127] = Wm[i];
  for (int i = 0; i < 4; i++) {
    int c = i * 16 + (tid >> 4);
    int n = (tid & 15) * 4;
    float4 v = *(const float4*)&x[((size_t)b * Cc + c) * Nn + n0 + n];
    *(float4*)&xs[c][n] = v;
  }
  __syncthreads();
  int o = tid & 63, ng = tid >> 6;              // ng == wave id -> nb uniform
  for (int p = 0; p < 4; p++) {
    int nb = p * 16 + ng * 4;
    float a1[4] = {0.f, 0.f, 0.f, 0.f};
    float a2[4] = {0.f, 0.f, 0.f, 0.f};
#pragma unroll 8
    for (int c = 0; c < 64; c++) {
      float4 xv = *(const float4*)&xs[c][nb];   // wave-broadcast
      float w1v = Wl[o][c], w2v = Wl[o][64 + c];
      float xa[4] = {xv.x, xv.y, xv.z, xv.w};
#pragma unroll
      for (int j = 0; j < 4; j++) {
        a1[j] = fmaf(xa[j], w1v, a1[j]);
        a2[j] = fmaf(xa[j], w2v, a2[j]);
      }
    }
#pragma unroll
    for (int j = 0; j < 4; j++) {
      size_t off = ((size_t)b * Nn + n0 + nb + j) * 64 + o;
      y1[off] = a1[j];
      z[off] = a2[j] - a1[j];
    }
  }
}

// ---------------------------------------------------------------- k_knn (v21)
// r8's best structure (237.4us), unchanged since r10: sub-tile double-buffer
// global_load_lds pipeline, XOR-linear staging, atomicAdd push, pair
// handlers, one-way threshold sharing (g1 takes min(thr1,thr0), r3-proven).
// All structural levers A/B-measured: ballot push +48us, quad drain +100us,
// bidir thresholds +26us (reverted); pipeline/conflict-fix/async neutral.
__global__ __launch_bounds__(512, 4) void k_knn(const unsigned short* __restrict__ xs3,
                                                const float* __restrict__ sqv,
                                                int* __restrict__ idxout) {
  __shared__ alignas(16) short Bs[2][2][6144];   // [grp][buf][32x192, XOR-swizzled]
  __shared__ alignas(16) float thrS[2][64];
  __shared__ alignas(16) float sqs[2][2][32];    // [grp][buf][col]
  __shared__ alignas(16) float qk[2][64][36];    // 144B rows: aligned + 2-way
  __shared__ alignas(16) unsigned short qm[2][64][40]; // 80B rows
  __shared__ int qcnt[2][64];

  const int tid = threadIdx.x;
  const int lane = tid & 63;
  const int w = tid >> 6;                        // 0..7
  const int grp = w >> 2;                        // m-range group
  const int wg = w & 3;                          // wave within group
  const int tig = tid & 255;                     // thread within group
  const int b = blockIdx.x & 7;                  // XCD swizzle: batch per XCD
  const int n0 = (blockIdx.x >> 3) << 6;         // 64 row-blocks x 64 rows
  const int lm = lane & 15;                      // candidate col / A row slot
  const int q = lane >> 4;                       // quad: C row = q*4+r
  const bool handler = (lane < 32);
  const int hrow = wg * 16 + (lane >> 1);        // row for this handler pair
  const bool isL = (lane & 1) == 0;              // L = ranks 0-9, H = 10-19
  const int rowq = wg * 16 + q * 4;              // my 4 push rows base

  // handler half-list: sorted ascending 10-list in registers
  float hk[Kh];
  int hix[Kh];
#pragma unroll
  for (int kk = 0; kk < Kh; kk++) { hk[kk] = INFINITY; hix[kk] = 0; }

  if (handler && !isL) { thrS[grp][hrow] = INFINITY; qcnt[grp][hrow] = 0; }

  // A fragments: wave owns 16 DISTINCT rows n0 + wg*16 + lm
  const size_t arow = ((size_t)(b << 12) + n0 + wg * 16 + lm) * 192;
  short8 ah0 = *(const short8*)&xs3[arow + q * 8];
  short8 ah1 = *(const short8*)&xs3[arow + 32 + q * 8];
  short8 am0 = *(const short8*)&xs3[arow + 64 + q * 8];
  short8 am1 = *(const short8*)&xs3[arow + 96 + q * 8];
  short8 al0 = *(const short8*)&xs3[arow + 128 + q * 8];
  short8 al1 = *(const short8*)&xs3[arow + 160 + q * 8];

  // ---- staging geometry: sub-tile = 32 rows x 24 granules = 768 granules.
  // LDS granule p holds global granule p ^ ((p/24)&7) (involution; rows are
  // 24 granules so aligned-8 blocks are row-pure). Wave wg, chunk i covers
  // LDS granules [i*256 + wg*64, +64): lane l -> p = that + l.
  const unsigned short* gbase = xs3 + ((size_t)(b << 12) + grp * 2048) * 192;
  int gofs[3];                                   // per-lane global short offs
  int lofs[3];                                   // wave-uniform LDS short offs
#pragma unroll
  for (int i = 0; i < 3; i++) {
    int p = i * 256 + wg * 64 + lane;
    gofs[i] = (p ^ ((p / 24) & 7)) * 8;
    lofs[i] = (i * 256 + wg * 64) * 8;
  }
  // B-fragment read XOR terms: row = g*16+lm -> row&7 == lm&7
  const int qa = ((q ^ (lm & 7)) << 3);          // granule q   (cols 0-31)
  const int qb = (((q + 4) ^ (lm & 7)) << 3);    // granule q+4 (cols 32-63)

  // prologue: stage sub-tile 0 into buf 0
#pragma unroll
  for (int i = 0; i < 3; i++) gload_lds16(gbase + gofs[i], &Bs[grp][0][lofs[i]]);
  if (tig < 8) gload_lds16(sqv + b * Nn + grp * 2048 + lane * 4, &sqs[grp][0][0]);

  int cur = 0;
  for (int t = 0; t < 64; t++) {
    const int m0 = grp * 2048 + t * 32;
    __syncthreads();             // buf[cur] loads landed; buf[cur^1] released
    if (t < 63) {                // prefetch next sub-tile under compute+drain
      const unsigned short* gn = gbase + 6144;
#pragma unroll
      for (int i = 0; i < 3; i++) gload_lds16(gn + gofs[i], &Bs[grp][cur ^ 1][lofs[i]]);
      if (tig < 8) gload_lds16(sqv + b * Nn + m0 + 32 + lane * 4, &sqs[grp][cur ^ 1][0]);
      gbase = gn;
    }

    const short* Bg = &Bs[grp][cur][0];
    f32x4 acc[2];
#pragma unroll
    for (int g = 0; g < 2; g++) {
      const short* brow = Bg + (g * 16 + lm) * 192;
      short8 bh0 = *(const short8*)(brow + qa);
      short8 bh1 = *(const short8*)(brow + qb);
      short8 bm0 = *(const short8*)(brow + 64 + qa);
      short8 bm1 = *(const short8*)(brow + 64 + qb);
      short8 bl0 = *(const short8*)(brow + 128 + qa);
      short8 bl1 = *(const short8*)(brow + 128 + qb);
      f32x4 a = (f32x4){0.f, 0.f, 0.f, 0.f};
      a = __builtin_amdgcn_mfma_f32_16x16x32_bf16(am0, bm0, a, 0, 0, 0);  // mm
      a = __builtin_amdgcn_mfma_f32_16x16x32_bf16(am1, bm1, a, 0, 0, 0);
      a = __builtin_amdgcn_mfma_f32_16x16x32_bf16(ah0, bl0, a, 0, 0, 0);  // hl
      a = __builtin_amdgcn_mfma_f32_16x16x32_bf16(ah1, bl1, a, 0, 0, 0);
      a = __builtin_amdgcn_mfma_f32_16x16x32_bf16(al0, bh0, a, 0, 0, 0);  // lh
      a = __builtin_amdgcn_mfma_f32_16x16x32_bf16(al1, bh1, a, 0, 0, 0);
      a = __builtin_amdgcn_mfma_f32_16x16x32_bf16(ah0, bm0, a, 0, 0, 0);  // hm
      a = __builtin_amdgcn_mfma_f32_16x16x32_bf16(ah1, bm1, a, 0, 0, 0);
      a = __builtin_amdgcn_mfma_f32_16x16x32_bf16(am0, bh0, a, 0, 0, 0);  // mh
      a = __builtin_amdgcn_mfma_f32_16x16x32_bf16(am1, bh1, a, 0, 0, 0);
      a = __builtin_amdgcn_mfma_f32_16x16x32_bf16(ah0, bh0, a, 0, 0, 0);  // hh
      a = __builtin_amdgcn_mfma_f32_16x16x32_bf16(ah1, bh1, a, 0, 0, 0);
      acc[g] = a;
    }

    // keys = sq[m] - 2*dot; 8 keys/lane (2 g x 4 r)
    unsigned pend = 0;
    {
      float4 t4 = *(const float4*)&thrS[grp][rowq];
      float tl[4] = {t4.x, t4.y, t4.z, t4.w};
      if (grp) {                                  // safe direction only (r3)
        float4 s4 = *(const float4*)&thrS[0][rowq];
        tl[0] = fminf(tl[0], s4.x); tl[1] = fminf(tl[1], s4.y);
        tl[2] = fminf(tl[2], s4.z); tl[3] = fminf(tl[3], s4.w);
      }
#pragma unroll
      for (int g = 0; g < 2; g++) {
        float sv = sqs[grp][cur][g * 16 + lm];
#pragma unroll
        for (int r = 0; r < 4; r++) {
          float key = fmaf(-2.f, acc[g][r], sv);
          acc[g][r] = key;
          if (key < tl[r]) pend |= 1u << (g * 4 + r);
        }
      }
    }

    // push: queue can't overflow (<=32 candidates/row, QCAP 32) -> no retry
    if (pend) {
#pragma unroll
      for (int g = 0; g < 2; g++) {
#pragma unroll
        for (int r = 0; r < 4; r++) {
          unsigned bit = 1u << (g * 4 + r);
          if (pend & bit) {
            int row = rowq + r;
            int p = atomicAdd(&qcnt[grp][row], 1);
            qk[grp][row][p] = acc[g][r];
            qm[grp][row][p] = (unsigned short)(m0 + g * 16 + lm);
          }
        }
      }
    }

    // single drain round (wave-private rows; DS in-order per wave)
    if (handler) {                               // 32 lanes: 16 rows x (L,H)
      int cn = qcnt[grp][hrow];                  // same for both pair lanes
      for (int p0 = 0; p0 < cn; p0 += 2) {
        float2 kv2 = *(const float2*)&qk[grp][hrow][p0];     // pair-broadcast
        ushort2 mv2 = *(const ushort2*)&qm[grp][hrow][p0];
        float kva[2] = {kv2.x, kv2.y};
        unsigned short mva[2] = {mv2.x, mv2.y};
#pragma unroll
        for (int j = 0; j < 2; j++) {
          bool valid = (p0 + j < cn);
          float kv = kva[j];
          int ki = (int)mva[j];
          // L decides what flows to H: its evicted max, or kv itself
          bool lins = kv < hk[Kh - 1];
          float pv_ = lins ? hk[Kh - 1] : kv;
          int pi_ = lins ? hix[Kh - 1] : ki;
          float rv = pair_swap_f(pv_);
          int ri = pair_swap_i(pi_);
          float mval = isL ? kv : rv;
          int midx = isL ? ki : ri;
          if (valid && mval < hk[Kh - 1]) {      // both roles: same 10-insert
            bool cm[Kh];
#pragma unroll
            for (int kk = 0; kk < Kh; kk++) cm[kk] = mval < hk[kk];
#pragma unroll
            for (int kk = Kh - 1; kk >= 1; kk--) {
              hk[kk]  = cm[kk] ? (cm[kk - 1] ? hk[kk - 1]  : mval) : hk[kk];
              hix[kk] = cm[kk] ? (cm[kk - 1] ? hix[kk - 1] : midx) : hix[kk];
            }
            if (cm[0]) { hk[0] = mval; hix[0] = midx; }
          }
        }
      }
      if (cn && !isL) { qcnt[grp][hrow] = 0; thrS[grp][hrow] = hk[Kh - 1]; }
    }
    cur ^= 1;
  }

  // -------- merge: group 1 publishes its rank-sorted 20-list per row
  if (grp == 1 && handler) {
    int base = isL ? 0 : Kh;
#pragma unroll
    for (int kk = 0; kk < Kh; kk++) {
      qk[1][hrow][base + kk] = hk[kk];
      qm[1][hrow][base + kk] = (unsigned short)hix[kk];
    }
  }
  __syncthreads();
  if (grp == 0 && handler) {
    // feed group 1's 20 candidates (ascending key order) through the same
    // pair-insert machinery; group-1 m-indices are all >= 2048 > any
    // group-0 index, so strict '<' keeps sequential-scan tie semantics
    for (int p0 = 0; p0 < Kk; p0 += 4) {
      float4 kv4 = *(const float4*)&qk[1][hrow][p0];
      ushort4 mv4 = *(const ushort4*)&qm[1][hrow][p0];
      float kva[4] = {kv4.x, kv4.y, kv4.z, kv4.w};
      unsigned short mva[4] = {mv4.x, mv4.y, mv4.z, mv4.w};
#pragma unroll
      for (int j = 0; j < 4; j++) {
        float kv = kva[j];
        int ki = (int)mva[j];
        bool lins = kv < hk[Kh - 1];
        float pv_ = lins ? hk[Kh - 1] : kv;
        int pi_ = lins ? hix[Kh - 1] : ki;
        float rv = pair_swap_f(pv_);
        int ri = pair_swap_i(pi_);
        float mval = isL ? kv : rv;
        int midx = isL ? ki : ri;
        if (mval < hk[Kh - 1]) {
          bool cm[Kh];
#pragma unroll
          for (int kk = 0; kk < Kh; kk++) cm[kk] = mval < hk[kk];
#pragma unroll
          for (int kk = Kh - 1; kk >= 1; kk--) {
            hk[kk]  = cm[kk] ? (cm[kk - 1] ? hk[kk - 1]  : mval) : hk[kk];
            hix[kk] = cm[kk] ? (cm[kk - 1] ? hix[kk - 1] : midx) : hix[kk];
          }
          if (cm[0]) { hk[0] = mval; hix[0] = midx; }
        }
      }
    }
    // final write: L lane writes ranks 0-9, H lane ranks 10-19
    size_t obase = ((size_t)b * Nn + n0 + hrow) * Kk + (isL ? 0 : Kh);
#pragma unroll
    for (int kk = 0; kk < Kh; kk++) idxout[obase + kk] = hix[kk];
  }
}

// ---------------------------------------------------------------- k_stats (v2)
// THE single gather pass (64-row tile — the 32-row occupancy variant
// MEASURED -48us WORSE in r12; reverted). On top of sum/sumsq, computes
// per-(n,o) max and min of hv (leaky-relu + channel affine are monotone,
// so k_out only needs these two extremes). Outputs transposed via LDS for
// coalesced writes: hmax into the out-buffer (scratch), hmin into ws.
__global__ __launch_bounds__(256) void k_stats(const float* __restrict__ y1,
                                               const float* __restrict__ z,
                                               const int* __restrict__ idxp,
                                               float* __restrict__ parts,
                                               float* __restrict__ hmax,
                                               float* __restrict__ hmin) {
  __shared__ float rs[4][64];
  __shared__ float rq[4][64];
  __shared__ float Tmx[64][65];
  __shared__ float Tmn[64][65];
  int tid = threadIdx.x;
  int o = tid & 63, g = tid >> 6;
  int b = blockIdx.x & 7;                       // XCD swizzle
  int n0 = (blockIdx.x >> 3) << 6;
  const float* y1b = y1 + (size_t)b * Nn * 64;
  float s = 0.f, ss = 0.f;
  for (int t = 0; t < 16; t++) {
    int nl = g + t * 4;
    size_t base = (size_t)b * Nn + n0 + nl;
    float zv = z[base * 64 + o];
    const int* ip = idxp + base * Kk;
    float mx = -INFINITY, mn = INFINITY;
#pragma unroll
    for (int k = 0; k < Kk; k++) {
      int j = ip[k];
      float hv = y1b[(size_t)j * 64 + o] + zv;
      s += hv;
      ss = fmaf(hv, hv, ss);
      mx = fmaxf(mx, hv);
      mn = fminf(mn, hv);
    }
    Tmx[o][nl] = mx;
    Tmn[o][nl] = mn;
  }
  rs[g][o] = s;
  rq[g][o] = ss;
  __syncthreads();
  if (tid < 64) {
    parts[(size_t)blockIdx.x * 128 + tid] = rs[0][tid] + rs[1][tid] + rs[2][tid] + rs[3][tid];
    parts[(size_t)blockIdx.x * 128 + 64 + tid] = rq[0][tid] + rq[1][tid] + rq[2][tid] + rq[3][tid];
  }
  int lane = tid & 63;
  for (int t = 0; t < 16; t++) {
    int oo = g * 16 + t;
    size_t ob = ((size_t)b * Oo + oo) * Nn + n0 + lane;
    hmax[ob] = Tmx[oo][lane];
    hmin[ob] = Tmn[oo][lane];
  }
}

// ---------------------------------------------------------------- k_reduce
// kept as a separate deterministic pass: atomicAdd folding would perturb
// the summation order (absmax sits exactly at 0.015625 -- do not disturb).
__global__ __launch_bounds__(128) void k_reduce(const float* __restrict__ parts,
                                                float* __restrict__ stats) {
  int tid = threadIdx.x;                         // [0,128)
  float s = 0.f;
  for (int i = 0; i < 512; i += 4) {
    s += parts[(size_t)i * 128 + tid] + parts[(size_t)(i + 1) * 128 + tid] +
         parts[(size_t)(i + 2) * 128 + tid] + parts[(size_t)(i + 3) * 128 + tid];
  }
  stats[tid] = s;
}

// ---------------------------------------------------------------- k_out (v2)
// Pure elementwise: max_k leaky(sc*hv+bi) = leaky(sc*(sc>=0?max:min)+bi)
// (leaky-relu monotone increasing; affine orientation from sign of sc).
// hmax lives in the out buffer -> in-place read/modify/write.
__global__ __launch_bounds__(256) void k_out(const float* __restrict__ hmax,
                                             const float* __restrict__ hmin,
                                             const float* __restrict__ stats,
                                             const float* __restrict__ gamma,
                                             const float* __restrict__ beta,
                                             float* __restrict__ out) {
  int idx4 = blockIdx.x * 256 + threadIdx.x;     // 2048 blocks x 256 = 524288
  int o = (idx4 >> 10) & 63;                     // Nn/4 = 1024 float4 per (b,o)
  const float inv = 1.0f / (float)NTOT;
  float mean = stats[o] * inv;
  float var = fmaf(-mean, mean, stats[64 + o] * inv);
  float sc = gamma[o] * rsqrtf(var + 1e-5f);
  float bi = fmaf(-mean, sc, beta[o]);
  float4 mx = ((const float4*)hmax)[idx4];
  float4 mn = ((const float4*)hmin)[idx4];
  float mxa[4] = {mx.x, mx.y, mx.z, mx.w};
  float mna[4] = {mn.x, mn.y, mn.z, mn.w};
  float4 r;
  float* rp = (float*)&r;
#pragma unroll
  for (int j = 0; j < 4; j++) {
    float v = (sc >= 0.f) ? mxa[j] : mna[j];
    float hn = fmaf(v, sc, bi);
    rp[j] = (hn >= 0.f) ? hn : 0.2f * hn;
  }
  ((float4*)out)[idx4] = r;
}

// ---------------------------------------------------------------- launch
extern "C" void kernel_launch(void* const* d_in, const int* in_sizes, int n_in,
                              void* d_out, int out_size, void* d_ws, size_t ws_size,
                              hipStream_t stream) {
  const float* x = (const float*)d_in[0];
  const float* W = (const float*)d_in[1];
  const float* gamma = (const float*)d_in[2];
  const float* beta = (const float*)d_in[3];
  // d_in[4] is k (=20), baked in as Kk.
  char* ws = (char*)d_ws;
  float* out = (float*)d_out;

  if (ws_size >= 32375296) {
    // ---- layout A (no xs3/y1 overlay -> k_split+k_y1z fused into k_pre):
    //   xs3  : [0,       12582912)   bf16 interleaved (dead after k_knn;
    //                                 hmin overlays [0, 8388608) in k_stats)
    //   y1   : [12582912,20971520)
    //   z    : [20971520,29360128)
    //   sq   : [29360128,29491200)
    //   stats: [29491200,29491712)
    //   idx20: [29491712,32113152)
    //   parts: [32113152,32375296)
    unsigned short* xs3 = (unsigned short*)ws;
    float* y1 = (float*)(ws + 12582912);
    float* z = (float*)(ws + 20971520);
    float* sq = (float*)(ws + 29360128);
    float* stats = (float*)(ws + 29491200);
    int* idx = (int*)(ws + 29491712);
    float* parts = (float*)(ws + 32113152);
    float* hmin = (float*)ws;                   // overlay dead xs3

    k_pre<<<Bn * (Nn / 64), 256, 0, stream>>>(x, W, xs3, sq, y1, z);
    k_knn<<<Bn * (Nn / 64), 512, 0, stream>>>(xs3, sq, idx);
    k_stats<<<Bn * (Nn / 64), 256, 0, stream>>>(y1, z, idx, parts, out, hmin);
    k_reduce<<<1, 128, 0, stream>>>(parts, stats);
    k_out<<<Bn * Oo * Nn / 1024, 256, 0, stream>>>(out, hmin, stats, gamma, beta, out);
  } else {
    // ---- layout B (r10 fallback; y1/z overlay xs3 -> k_y1z after k_knn):
    //   xs3 [0,12582912) / y1 [0,8388608) / z [8388608,16777216)
    //   sq [16777216,16908288) / stats [16908288,16908800)
    //   idx [16908800,19530240) / parts [19530240,19792384)
    //   hmin [19792384,28180992)
    unsigned short* xs3 = (unsigned short*)ws;
    float* y1 = (float*)ws;
    float* z = (float*)(ws + 8388608);
    float* sq = (float*)(ws + 16777216);
    float* stats = (float*)(ws + 16908288);
    int* idx = (int*)(ws + 16908800);
    float* parts = (float*)(ws + 19530240);
    float* hmin = (float*)(ws + 19792384);

    k_split<<<Bn * (Nn / 64), 256, 0, stream>>>(x, xs3, sq);
    k_knn<<<Bn * (Nn / 64), 512, 0, stream>>>(xs3, sq, idx);
    k_y1z<<<Bn * (Nn / 64), 256, 0, stream>>>(x, W, y1, z);
    k_stats<<<Bn * (Nn / 64), 256, 0, stream>>>(y1, z, idx, parts, out, hmin);
    k_reduce<<<1, 128, 0, stream>>>(parts, stats);
    k_out<<<Bn * Oo * Nn / 1024, 256, 0, stream>>>(out, hmin, stats, gamma, beta, out);
  }
}